// Round 1
// baseline (494.642 us; speedup 1.0000x reference)
//
#include <hip/hip_runtime.h>

#define N_NODES 50000
#define N_EDGES 600000
#define N_GRAPHS 64
#define IN_D 5
#define HID 128
#define EMB 64

#define CHUNK 512
#define NCHUNK ((N_NODES + CHUNK - 1) / CHUNK)   // 98

// ---------- CSR build ----------

__global__ void k_count(const int* __restrict__ dst, int* __restrict__ cnt) {
    int e = blockIdx.x * blockDim.x + threadIdx.x;
    if (e < N_EDGES) atomicAdd(&cnt[dst[e]], 1);
}

__global__ void k_dinv(const int* __restrict__ cnt, float* __restrict__ dinv) {
    int i = blockIdx.x * blockDim.x + threadIdx.x;
    if (i < N_NODES) dinv[i] = rsqrtf((float)cnt[i] + 1.0f);  // +1 self-loop
}

__global__ void k_chunksum(const int* __restrict__ cnt, int* __restrict__ csum) {
    __shared__ int sh[256];
    int b = blockIdx.x, t = threadIdx.x;
    int i0 = b * CHUNK + t, i1 = i0 + 256;
    int v = 0;
    if (i0 < N_NODES) v += cnt[i0];
    if (i1 < N_NODES) v += cnt[i1];
    sh[t] = v; __syncthreads();
    for (int off = 128; off > 0; off >>= 1) {
        if (t < off) sh[t] += sh[t + off];
        __syncthreads();
    }
    if (t == 0) csum[b] = sh[0];
}

__global__ void k_scanchunks(int* __restrict__ csum, int* __restrict__ row_start) {
    if (threadIdx.x == 0) {
        int run = 0;
        for (int c = 0; c < NCHUNK; ++c) { int v = csum[c]; csum[c] = run; run += v; }
        row_start[N_NODES] = N_EDGES;
    }
}

__global__ void k_scan(const int* __restrict__ cnt, const int* __restrict__ csum,
                       int* __restrict__ row_start) {
    __shared__ int sh[CHUNK];
    int b = blockIdx.x, t = threadIdx.x;
    int i = b * CHUNK + t;
    int v = (i < N_NODES) ? cnt[i] : 0;
    sh[t] = v; __syncthreads();
    for (int off = 1; off < CHUNK; off <<= 1) {
        int x = (t >= off) ? sh[t - off] : 0;
        __syncthreads();
        sh[t] += x;
        __syncthreads();
    }
    if (i < N_NODES) row_start[i] = sh[t] - v + csum[b];  // exclusive
}

__global__ void k_scatter(const int* __restrict__ src, const int* __restrict__ dst,
                          const float* __restrict__ dinv,
                          const int* __restrict__ row_start, int* __restrict__ fill,
                          int2* __restrict__ e_pack) {
    int e = blockIdx.x * blockDim.x + threadIdx.x;
    if (e >= N_EDGES) return;
    int d = dst[e];
    int pos = row_start[d] + atomicAdd(&fill[d], 1);
    int s = src[e];
    e_pack[pos] = make_int2(s, __float_as_int(dinv[s]));
}

// ---------- aggregation ----------

// aggregate raw x (N,5): thread per node
__global__ void k_agg5(const float* __restrict__ x, const float* __restrict__ dinv,
                       const int* __restrict__ row_start,
                       const int2* __restrict__ e_pack, float* __restrict__ out) {
    int i = blockIdx.x * blockDim.x + threadIdx.x;
    if (i >= N_NODES) return;
    float acc[IN_D] = {0.f, 0.f, 0.f, 0.f, 0.f};
    int beg = row_start[i], end = row_start[i + 1];
    for (int e = beg; e < end; ++e) {
        int2 p = e_pack[e];
        const float* xr = x + p.x * IN_D;
        float w = __int_as_float(p.y);
        #pragma unroll
        for (int k = 0; k < IN_D; ++k) acc[k] += w * xr[k];
    }
    float di = dinv[i];
    const float* xi = x + i * IN_D;
    #pragma unroll
    for (int k = 0; k < IN_D; ++k) out[i * IN_D + k] = di * (acc[k] + di * xi[k]);
}

// aggregate H (N,128): one wave per node, float2 per lane
__global__ __launch_bounds__(256) void k_agg128(
        const float* __restrict__ H, const float* __restrict__ dinv,
        const int* __restrict__ row_start, const int2* __restrict__ e_pack,
        float* __restrict__ out) {
    int wid = (blockIdx.x * blockDim.x + threadIdx.x) >> 6;
    int lane = threadIdx.x & 63;
    if (wid >= N_NODES) return;
    const float2* H2 = (const float2*)H;
    float2 acc = make_float2(0.f, 0.f);
    int beg = row_start[wid], end = row_start[wid + 1];
    for (int e = beg; e < end; ++e) {
        int2 p = e_pack[e];
        float w = __int_as_float(p.y);
        float2 h = H2[(size_t)p.x * 64 + lane];
        acc.x = fmaf(w, h.x, acc.x);
        acc.y = fmaf(w, h.y, acc.y);
    }
    float di = dinv[wid];
    float2 hs = H2[(size_t)wid * 64 + lane];
    acc.x = fmaf(di, hs.x, acc.x);
    acc.y = fmaf(di, hs.y, acc.y);
    float2* O2 = (float2*)out;
    O2[(size_t)wid * 64 + lane] = make_float2(di * acc.x, di * acc.y);
}

// ---------- GEMMs with fused bias + BN(eval) + ReLU ----------

// layer1: (N,5)@(5,128): thread per output
__global__ void k_gemm1(const float* __restrict__ A, const float* __restrict__ W,
                        const float* __restrict__ b, const float* __restrict__ g,
                        const float* __restrict__ be, float* __restrict__ out) {
    int gid = blockIdx.x * blockDim.x + threadIdx.x;
    if (gid >= N_NODES * HID) return;
    int n = gid >> 7, f = gid & 127;
    const float* a = A + n * IN_D;
    float acc = b[f];
    #pragma unroll
    for (int k = 0; k < IN_D; ++k) acc = fmaf(a[k], W[k * HID + f], acc);
    const float rs = rsqrtf(1.0f + 1e-5f);
    float v = fmaf(acc, g[f] * rs, be[f]);
    out[gid] = v > 0.0f ? v : 0.0f;
}

// (N,128)@(128,128): block = 64 nodes x 64 feats, 256 threads, 64KB LDS
__global__ __launch_bounds__(256) void k_gemm128(
        const float* __restrict__ A, const float* __restrict__ W,
        const float* __restrict__ b, const float* __restrict__ g,
        const float* __restrict__ be, float* __restrict__ out) {
    __shared__ float4 sW[128 * 16];  // [k][f4 within half] 32KB
    __shared__ float4 sA[64 * 32];   // [n][k4] 32KB
    int t = threadIdx.x;
    int nb = blockIdx.x * 64;
    int fb4 = blockIdx.y * 16;       // feat-half base in float4 units
    const float4* W4 = (const float4*)W;
    const float4* A4 = (const float4*)A;
    #pragma unroll
    for (int i = 0; i < 8; ++i) {
        int q = t + i * 256;                 // [0,2048)
        int k = q >> 4, fv = q & 15;
        sW[q] = W4[k * 32 + fb4 + fv];
        int nl = q >> 5, kv = q & 31;
        int n = nb + nl;
        sA[q] = (n < N_NODES) ? A4[(size_t)n * 32 + kv] : make_float4(0.f, 0.f, 0.f, 0.f);
    }
    __syncthreads();
    int fi = t & 15;       // f4 within half
    int nsub = t >> 4;     // 0..15 ; nodes nsub + 16m
    float4 acc[4];
    #pragma unroll
    for (int m = 0; m < 4; ++m) acc[m] = make_float4(0.f, 0.f, 0.f, 0.f);
    for (int k4 = 0; k4 < 32; ++k4) {
        float4 a[4];
        #pragma unroll
        for (int m = 0; m < 4; ++m) a[m] = sA[(nsub + m * 16) * 32 + k4];
        #pragma unroll
        for (int j = 0; j < 4; ++j) {
            float4 w = sW[(k4 * 4 + j) * 16 + fi];
            #pragma unroll
            for (int m = 0; m < 4; ++m) {
                float aj = (j == 0) ? a[m].x : (j == 1) ? a[m].y : (j == 2) ? a[m].z : a[m].w;
                acc[m].x = fmaf(aj, w.x, acc[m].x);
                acc[m].y = fmaf(aj, w.y, acc[m].y);
                acc[m].z = fmaf(aj, w.z, acc[m].z);
                acc[m].w = fmaf(aj, w.w, acc[m].w);
            }
        }
    }
    const float rs = rsqrtf(1.0f + 1e-5f);
    float4 b4  = ((const float4*)b)[fb4 + fi];
    float4 g4  = ((const float4*)g)[fb4 + fi];
    float4 be4 = ((const float4*)be)[fb4 + fi];
    g4.x *= rs; g4.y *= rs; g4.z *= rs; g4.w *= rs;
    float4* O4 = (float4*)out;
    #pragma unroll
    for (int m = 0; m < 4; ++m) {
        int n = nb + nsub + m * 16;
        if (n < N_NODES) {
            float4 v;
            v.x = fmaf(acc[m].x + b4.x, g4.x, be4.x);
            v.y = fmaf(acc[m].y + b4.y, g4.y, be4.y);
            v.z = fmaf(acc[m].z + b4.z, g4.z, be4.z);
            v.w = fmaf(acc[m].w + b4.w, g4.w, be4.w);
            v.x = v.x > 0.f ? v.x : 0.f;
            v.y = v.y > 0.f ? v.y : 0.f;
            v.z = v.z > 0.f ? v.z : 0.f;
            v.w = v.w > 0.f ? v.w : 0.f;
            O4[(size_t)n * 32 + fb4 + fi] = v;
        }
    }
}

// ---------- pooling + projection ----------

#define PCHUNK 512
__global__ void k_pool(const float* __restrict__ H, const int* __restrict__ batch,
                       float* __restrict__ sums, float* __restrict__ cntf) {
    int b = blockIdx.x, t = threadIdx.x;
    int f = t & 127, hv = t >> 7;   // hv = 0/1 node parity
    int n0 = b * PCHUNK + hv;
    int nend = min(b * PCHUNK + PCHUNK, N_NODES);
    float acc = 0.f, c = 0.f;
    int cur = -1;
    for (int n = n0; n < nend; n += 2) {
        int gi = batch[n];
        if (gi != cur) {
            if (cur >= 0) {
                atomicAdd(&sums[cur * HID + f], acc);
                if (f == 0) atomicAdd(&cntf[cur], c);
            }
            acc = 0.f; c = 0.f; cur = gi;
        }
        acc += H[(size_t)n * HID + f];
        c += 1.f;
    }
    if (cur >= 0) {
        atomicAdd(&sums[cur * HID + f], acc);
        if (f == 0) atomicAdd(&cntf[cur], c);
    }
}

__global__ void k_final(const float* __restrict__ sums, const float* __restrict__ cntf,
                        const float* __restrict__ Wp, const float* __restrict__ bp,
                        float* __restrict__ out) {
    int gi = blockIdx.x, e = threadIdx.x;
    float inv = 1.0f / fmaxf(cntf[gi], 1.0f);
    float acc = bp[e];
    for (int f = 0; f < HID; ++f)
        acc = fmaf(sums[gi * HID + f] * inv, Wp[f * EMB + e], acc);
    out[gi * EMB + e] = acc;
}

// ---------- launcher ----------

extern "C" void kernel_launch(void* const* d_in, const int* in_sizes, int n_in,
                              void* d_out, int out_size, void* d_ws, size_t ws_size,
                              hipStream_t stream) {
    const float* x   = (const float*)d_in[0];
    const int*   src = (const int*)d_in[1];
    const int*   dst = (const int*)d_in[2];
    const int* batch = (const int*)d_in[3];
    const float* W1 = (const float*)d_in[4];
    const float* b1 = (const float*)d_in[5];
    const float* W2 = (const float*)d_in[6];
    const float* b2 = (const float*)d_in[7];
    const float* W3 = (const float*)d_in[8];
    const float* b3 = (const float*)d_in[9];
    const float* g1 = (const float*)d_in[10];
    const float* be1 = (const float*)d_in[11];
    const float* g2 = (const float*)d_in[12];
    const float* be2 = (const float*)d_in[13];
    const float* g3 = (const float*)d_in[14];
    const float* be3 = (const float*)d_in[15];
    const float* Wp = (const float*)d_in[16];
    const float* bp = (const float*)d_in[17];
    float* out = (float*)d_out;

    char* ws = (char*)d_ws;
    size_t o = 0;
    auto alloc = [&](size_t elems) {
        void* p = ws + o;
        o += elems * 4;
        o = (o + 15) & ~15ull;
        return p;
    };
    int*   cnt_e     = (int*)alloc(N_NODES);
    int*   row_start = (int*)alloc(N_NODES + 1);
    int*   csum      = (int*)alloc(NCHUNK);
    float* dinv      = (float*)alloc(N_NODES);
    int2*  e_pack    = (int2*)alloc(2 * (size_t)N_EDGES);
    float* agg5      = (float*)alloc((size_t)N_NODES * IN_D);
    float* bufA      = (float*)alloc((size_t)N_NODES * HID);
    float* bufB      = (float*)alloc((size_t)N_NODES * HID);
    float* psum      = (float*)alloc(N_GRAPHS * HID);
    float* pcnt      = (float*)alloc(N_GRAPHS);

    hipMemsetAsync(cnt_e, 0, N_NODES * 4, stream);
    k_count<<<(N_EDGES + 255) / 256, 256, 0, stream>>>(dst, cnt_e);
    k_dinv<<<(N_NODES + 255) / 256, 256, 0, stream>>>(cnt_e, dinv);
    k_chunksum<<<NCHUNK, 256, 0, stream>>>(cnt_e, csum);
    k_scanchunks<<<1, 64, 0, stream>>>(csum, row_start);
    k_scan<<<NCHUNK, CHUNK, 0, stream>>>(cnt_e, csum, row_start);
    hipMemsetAsync(cnt_e, 0, N_NODES * 4, stream);  // reuse as fill counters
    k_scatter<<<(N_EDGES + 255) / 256, 256, 0, stream>>>(src, dst, dinv, row_start,
                                                         cnt_e, e_pack);

    // layer 1: aggregate(x) -> gemm1 + bn + relu -> bufA
    k_agg5<<<(N_NODES + 255) / 256, 256, 0, stream>>>(x, dinv, row_start, e_pack, agg5);
    k_gemm1<<<(N_NODES * HID + 255) / 256, 256, 0, stream>>>(agg5, W1, b1, g1, be1, bufA);

    // layer 2
    k_agg128<<<(N_NODES * 64 + 255) / 256, 256, 0, stream>>>(bufA, dinv, row_start,
                                                             e_pack, bufB);
    {
        dim3 grid((N_NODES + 63) / 64, 2);
        k_gemm128<<<grid, 256, 0, stream>>>(bufB, W2, b2, g2, be2, bufA);
    }
    // layer 3
    k_agg128<<<(N_NODES * 64 + 255) / 256, 256, 0, stream>>>(bufA, dinv, row_start,
                                                             e_pack, bufB);
    {
        dim3 grid((N_NODES + 63) / 64, 2);
        k_gemm128<<<grid, 256, 0, stream>>>(bufB, W3, b3, g3, be3, bufA);
    }

    // pool + project
    hipMemsetAsync(psum, 0, (N_GRAPHS * HID + N_GRAPHS) * 4, stream);
    k_pool<<<(N_NODES + PCHUNK - 1) / PCHUNK, 256, 0, stream>>>(bufA, batch, psum, pcnt);
    k_final<<<N_GRAPHS, EMB, 0, stream>>>(psum, pcnt, Wp, bp, out);
}

// Round 2
// 400.344 us; speedup vs baseline: 1.2355x; 1.2355x over previous
//
#include <hip/hip_runtime.h>

#define N_NODES 50000
#define N_EDGES 600000
#define N_GRAPHS 64
#define IN_D 5
#define HID 128
#define EMB 64

#define CHUNK 512
#define NCHUNK ((N_NODES + CHUNK - 1) / CHUNK)   // 98

// ---------- CSR build ----------

__global__ void k_count(const int* __restrict__ dst, int* __restrict__ cnt) {
    int e = blockIdx.x * blockDim.x + threadIdx.x;
    if (e < N_EDGES) atomicAdd(&cnt[dst[e]], 1);
}

// per-chunk sums for scan + dinv computation (merged)
__global__ void k_chunksum(const int* __restrict__ cnt, int* __restrict__ csum,
                           float* __restrict__ dinv) {
    __shared__ int sh[256];
    int b = blockIdx.x, t = threadIdx.x;
    int i0 = b * CHUNK + t, i1 = i0 + 256;
    int v = 0;
    if (i0 < N_NODES) { int c = cnt[i0]; v += c; dinv[i0] = rsqrtf((float)c + 1.0f); }
    if (i1 < N_NODES) { int c = cnt[i1]; v += c; dinv[i1] = rsqrtf((float)c + 1.0f); }
    sh[t] = v; __syncthreads();
    for (int off = 128; off > 0; off >>= 1) {
        if (t < off) sh[t] += sh[t + off];
        __syncthreads();
    }
    if (t == 0) csum[b] = sh[0];
}

// single-wave shuffle scan over the 98 chunk sums (was: single-thread serial loop)
__global__ void k_scanchunks(int* __restrict__ csum, int* __restrict__ row_start) {
    int lane = threadIdx.x;
    int v0 = (lane < NCHUNK) ? csum[lane] : 0;
    int v1 = (lane + 64 < NCHUNK) ? csum[lane + 64] : 0;
    int s0 = v0;
    #pragma unroll
    for (int off = 1; off < 64; off <<= 1) {
        int u = __shfl_up(s0, off);
        if (lane >= off) s0 += u;
    }
    int tot0 = __shfl(s0, 63);
    int s1 = v1;
    #pragma unroll
    for (int off = 1; off < 64; off <<= 1) {
        int u = __shfl_up(s1, off);
        if (lane >= off) s1 += u;
    }
    if (lane < NCHUNK) csum[lane] = s0 - v0;                    // exclusive
    if (lane + 64 < NCHUNK) csum[lane + 64] = tot0 + s1 - v1;
    if (lane == 0) row_start[N_NODES] = N_EDGES;
}

// per-chunk exclusive scan: wave shuffle scans + 2 barriers (was 18-barrier Hillis-Steele)
__global__ void k_scan(const int* __restrict__ cnt, const int* __restrict__ csum,
                       int* __restrict__ row_start) {
    __shared__ int ws[8];
    int b = blockIdx.x, t = threadIdx.x;
    int lane = t & 63, w = t >> 6;
    int i = b * CHUNK + t;
    int v = (i < N_NODES) ? cnt[i] : 0;
    int s = v;
    #pragma unroll
    for (int off = 1; off < 64; off <<= 1) {
        int u = __shfl_up(s, off);
        if (lane >= off) s += u;
    }
    if (lane == 63) ws[w] = s;
    __syncthreads();
    if (w == 0) {
        int x = (lane < 8) ? ws[lane] : 0;
        int sx = x;
        #pragma unroll
        for (int off = 1; off < 8; off <<= 1) {
            int u = __shfl_up(sx, off);
            if (lane >= off) sx += u;
        }
        if (lane < 8) ws[lane] = sx - x;   // exclusive wave offsets
    }
    __syncthreads();
    if (i < N_NODES) row_start[i] = s - v + ws[w] + csum[b];   // exclusive
}

__global__ void k_scatter(const int* __restrict__ src, const int* __restrict__ dst,
                          const float* __restrict__ dinv,
                          const int* __restrict__ row_start, int* __restrict__ fill,
                          int2* __restrict__ e_pack) {
    int e = blockIdx.x * blockDim.x + threadIdx.x;
    if (e >= N_EDGES) return;
    int d = dst[e];
    int pos = row_start[d] + atomicAdd(&fill[d], 1);
    int s = src[e];
    e_pack[pos] = make_int2(s, __float_as_int(dinv[s]));
}

// ---------- aggregation ----------

// aggregate raw x (N,5): 8 threads per node (k = lane 0..4 active)
__global__ void k_agg5(const float* __restrict__ x, const float* __restrict__ dinv,
                       const int* __restrict__ row_start,
                       const int2* __restrict__ e_pack, float* __restrict__ out) {
    int gid = blockIdx.x * blockDim.x + threadIdx.x;
    int i = gid >> 3, k = gid & 7;
    if (i >= N_NODES || k >= IN_D) return;
    float acc = 0.f;
    int beg = row_start[i], end = row_start[i + 1];
    for (int e = beg; e < end; ++e) {
        int2 p = e_pack[e];
        acc = fmaf(__int_as_float(p.y), x[p.x * IN_D + k], acc);
    }
    float di = dinv[i];
    out[i * IN_D + k] = di * (acc + di * x[i * IN_D + k]);
}

// aggregate H (N,128): one wave per node, float2 per lane, edge loop unrolled x2
__global__ __launch_bounds__(256) void k_agg128(
        const float* __restrict__ H, const float* __restrict__ dinv,
        const int* __restrict__ row_start, const int2* __restrict__ e_pack,
        float* __restrict__ out) {
    int wid = (blockIdx.x * blockDim.x + threadIdx.x) >> 6;
    int lane = threadIdx.x & 63;
    if (wid >= N_NODES) return;
    const float2* H2 = (const float2*)H;
    float2 acc = make_float2(0.f, 0.f);
    int beg = row_start[wid], end = row_start[wid + 1];
    int e = beg;
    for (; e + 1 < end; e += 2) {
        int2 p0 = e_pack[e];
        int2 p1 = e_pack[e + 1];
        float2 h0 = H2[(size_t)p0.x * 64 + lane];
        float2 h1 = H2[(size_t)p1.x * 64 + lane];
        float w0 = __int_as_float(p0.y), w1 = __int_as_float(p1.y);
        acc.x = fmaf(w0, h0.x, acc.x);
        acc.y = fmaf(w0, h0.y, acc.y);
        acc.x = fmaf(w1, h1.x, acc.x);
        acc.y = fmaf(w1, h1.y, acc.y);
    }
    if (e < end) {
        int2 p = e_pack[e];
        float w = __int_as_float(p.y);
        float2 h = H2[(size_t)p.x * 64 + lane];
        acc.x = fmaf(w, h.x, acc.x);
        acc.y = fmaf(w, h.y, acc.y);
    }
    float di = dinv[wid];
    float2 hs = H2[(size_t)wid * 64 + lane];
    acc.x = fmaf(di, hs.x, acc.x);
    acc.y = fmaf(di, hs.y, acc.y);
    float2* O2 = (float2*)out;
    O2[(size_t)wid * 64 + lane] = make_float2(di * acc.x, di * acc.y);
}

// ---------- GEMMs with fused bias + BN(eval) + ReLU ----------

__global__ void k_gemm1(const float* __restrict__ A, const float* __restrict__ W,
                        const float* __restrict__ b, const float* __restrict__ g,
                        const float* __restrict__ be, float* __restrict__ out) {
    int gid = blockIdx.x * blockDim.x + threadIdx.x;
    if (gid >= N_NODES * HID) return;
    int n = gid >> 7, f = gid & 127;
    const float* a = A + n * IN_D;
    float acc = b[f];
    #pragma unroll
    for (int k = 0; k < IN_D; ++k) acc = fmaf(a[k], W[k * HID + f], acc);
    const float rs = rsqrtf(1.0f + 1e-5f);
    float v = fmaf(acc, g[f] * rs, be[f]);
    out[gid] = v > 0.0f ? v : 0.0f;
}

// (N,128)@(128,128): block = 64 nodes x 64 feats, 256 threads, 64KB LDS
__global__ __launch_bounds__(256) void k_gemm128(
        const float* __restrict__ A, const float* __restrict__ W,
        const float* __restrict__ b, const float* __restrict__ g,
        const float* __restrict__ be, float* __restrict__ out) {
    __shared__ float4 sW[128 * 16];  // [k][f4 within half] 32KB
    __shared__ float4 sA[64 * 32];   // [n][k4] 32KB
    int t = threadIdx.x;
    int nb = blockIdx.x * 64;
    int fb4 = blockIdx.y * 16;       // feat-half base in float4 units
    const float4* W4 = (const float4*)W;
    const float4* A4 = (const float4*)A;
    #pragma unroll
    for (int i = 0; i < 8; ++i) {
        int q = t + i * 256;                 // [0,2048)
        int k = q >> 4, fv = q & 15;
        sW[q] = W4[k * 32 + fb4 + fv];
        int nl = q >> 5, kv = q & 31;
        int n = nb + nl;
        sA[q] = (n < N_NODES) ? A4[(size_t)n * 32 + kv] : make_float4(0.f, 0.f, 0.f, 0.f);
    }
    __syncthreads();
    int fi = t & 15;       // f4 within half
    int nsub = t >> 4;     // 0..15 ; nodes nsub + 16m
    float4 acc[4];
    #pragma unroll
    for (int m = 0; m < 4; ++m) acc[m] = make_float4(0.f, 0.f, 0.f, 0.f);
    for (int k4 = 0; k4 < 32; ++k4) {
        float4 a[4];
        #pragma unroll
        for (int m = 0; m < 4; ++m) a[m] = sA[(nsub + m * 16) * 32 + k4];
        #pragma unroll
        for (int j = 0; j < 4; ++j) {
            float4 w = sW[(k4 * 4 + j) * 16 + fi];
            #pragma unroll
            for (int m = 0; m < 4; ++m) {
                float aj = (j == 0) ? a[m].x : (j == 1) ? a[m].y : (j == 2) ? a[m].z : a[m].w;
                acc[m].x = fmaf(aj, w.x, acc[m].x);
                acc[m].y = fmaf(aj, w.y, acc[m].y);
                acc[m].z = fmaf(aj, w.z, acc[m].z);
                acc[m].w = fmaf(aj, w.w, acc[m].w);
            }
        }
    }
    const float rs = rsqrtf(1.0f + 1e-5f);
    float4 b4  = ((const float4*)b)[fb4 + fi];
    float4 g4  = ((const float4*)g)[fb4 + fi];
    float4 be4 = ((const float4*)be)[fb4 + fi];
    g4.x *= rs; g4.y *= rs; g4.z *= rs; g4.w *= rs;
    float4* O4 = (float4*)out;
    #pragma unroll
    for (int m = 0; m < 4; ++m) {
        int n = nb + nsub + m * 16;
        if (n < N_NODES) {
            float4 v;
            v.x = fmaf(acc[m].x + b4.x, g4.x, be4.x);
            v.y = fmaf(acc[m].y + b4.y, g4.y, be4.y);
            v.z = fmaf(acc[m].z + b4.z, g4.z, be4.z);
            v.w = fmaf(acc[m].w + b4.w, g4.w, be4.w);
            v.x = v.x > 0.f ? v.x : 0.f;
            v.y = v.y > 0.f ? v.y : 0.f;
            v.z = v.z > 0.f ? v.z : 0.f;
            v.w = v.w > 0.f ? v.w : 0.f;
            O4[(size_t)n * 32 + fb4 + fi] = v;
        }
    }
}

// ---------- pooling + projection ----------

// PCHUNK=64: 782 blocks (was 98) — kills the latency-bound serial loop
#define PCHUNK 64
__global__ __launch_bounds__(256) void k_pool(
        const float* __restrict__ H, const int* __restrict__ batch,
        float* __restrict__ sums, float* __restrict__ cntf) {
    int b = blockIdx.x, t = threadIdx.x;
    int f = t & 127, hv = t >> 7;   // hv = 0/1 node parity
    int n0 = b * PCHUNK + hv;
    int nend = min(b * PCHUNK + PCHUNK, N_NODES);
    float acc = 0.f, c = 0.f;
    int cur = -1;
    for (int n = n0; n < nend; n += 2) {
        int gi = batch[n];
        if (gi != cur) {
            if (cur >= 0) {
                atomicAdd(&sums[cur * HID + f], acc);
                if (f == 0) atomicAdd(&cntf[cur], c);
            }
            acc = 0.f; c = 0.f; cur = gi;
        }
        acc += H[(size_t)n * HID + f];
        c += 1.f;
    }
    if (cur >= 0) {
        atomicAdd(&sums[cur * HID + f], acc);
        if (f == 0) atomicAdd(&cntf[cur], c);
    }
}

__global__ void k_final(const float* __restrict__ sums, const float* __restrict__ cntf,
                        const float* __restrict__ Wp, const float* __restrict__ bp,
                        float* __restrict__ out) {
    int gi = blockIdx.x, e = threadIdx.x;
    float inv = 1.0f / fmaxf(cntf[gi], 1.0f);
    float acc = bp[e];
    #pragma unroll 8
    for (int f = 0; f < HID; ++f)
        acc = fmaf(sums[gi * HID + f] * inv, Wp[f * EMB + e], acc);
    out[gi * EMB + e] = acc;
}

// ---------- launcher ----------

extern "C" void kernel_launch(void* const* d_in, const int* in_sizes, int n_in,
                              void* d_out, int out_size, void* d_ws, size_t ws_size,
                              hipStream_t stream) {
    const float* x   = (const float*)d_in[0];
    const int*   src = (const int*)d_in[1];
    const int*   dst = (const int*)d_in[2];
    const int* batch = (const int*)d_in[3];
    const float* W1 = (const float*)d_in[4];
    const float* b1 = (const float*)d_in[5];
    const float* W2 = (const float*)d_in[6];
    const float* b2 = (const float*)d_in[7];
    const float* W3 = (const float*)d_in[8];
    const float* b3 = (const float*)d_in[9];
    const float* g1 = (const float*)d_in[10];
    const float* be1 = (const float*)d_in[11];
    const float* g2 = (const float*)d_in[12];
    const float* be2 = (const float*)d_in[13];
    const float* g3 = (const float*)d_in[14];
    const float* be3 = (const float*)d_in[15];
    const float* Wp = (const float*)d_in[16];
    const float* bp = (const float*)d_in[17];
    float* out = (float*)d_out;

    char* ws = (char*)d_ws;
    size_t o = 0;
    auto alloc = [&](size_t elems) {
        void* p = ws + o;
        o += elems * 4;
        o = (o + 15) & ~15ull;
        return p;
    };
    int*   cnt_e     = (int*)alloc(N_NODES);
    int*   row_start = (int*)alloc(N_NODES + 1);
    int*   csum      = (int*)alloc(NCHUNK);
    float* dinv      = (float*)alloc(N_NODES);
    int2*  e_pack    = (int2*)alloc(2 * (size_t)N_EDGES);
    float* agg5      = (float*)alloc((size_t)N_NODES * IN_D);
    float* bufA      = (float*)alloc((size_t)N_NODES * HID);
    float* bufB      = (float*)alloc((size_t)N_NODES * HID);
    float* psum      = (float*)alloc(N_GRAPHS * HID);
    float* pcnt      = (float*)alloc(N_GRAPHS);

    hipMemsetAsync(cnt_e, 0, N_NODES * 4, stream);
    k_count<<<(N_EDGES + 255) / 256, 256, 0, stream>>>(dst, cnt_e);
    k_chunksum<<<NCHUNK, 256, 0, stream>>>(cnt_e, csum, dinv);
    k_scanchunks<<<1, 64, 0, stream>>>(csum, row_start);
    k_scan<<<NCHUNK, CHUNK, 0, stream>>>(cnt_e, csum, row_start);
    hipMemsetAsync(cnt_e, 0, N_NODES * 4, stream);  // reuse as fill counters
    k_scatter<<<(N_EDGES + 255) / 256, 256, 0, stream>>>(src, dst, dinv, row_start,
                                                         cnt_e, e_pack);

    // layer 1: aggregate(x) -> gemm1 + bn + relu -> bufA
    k_agg5<<<(N_NODES * 8 + 255) / 256, 256, 0, stream>>>(x, dinv, row_start, e_pack, agg5);
    k_gemm1<<<(N_NODES * HID + 255) / 256, 256, 0, stream>>>(agg5, W1, b1, g1, be1, bufA);

    // layer 2
    k_agg128<<<(N_NODES * 64 + 255) / 256, 256, 0, stream>>>(bufA, dinv, row_start,
                                                             e_pack, bufB);
    {
        dim3 grid((N_NODES + 63) / 64, 2);
        k_gemm128<<<grid, 256, 0, stream>>>(bufB, W2, b2, g2, be2, bufA);
    }
    // layer 3
    k_agg128<<<(N_NODES * 64 + 255) / 256, 256, 0, stream>>>(bufA, dinv, row_start,
                                                             e_pack, bufB);
    {
        dim3 grid((N_NODES + 63) / 64, 2);
        k_gemm128<<<grid, 256, 0, stream>>>(bufB, W3, b3, g3, be3, bufA);
    }

    // pool + project
    hipMemsetAsync(psum, 0, (N_GRAPHS * HID + N_GRAPHS) * 4, stream);
    k_pool<<<(N_NODES + PCHUNK - 1) / PCHUNK, 256, 0, stream>>>(bufA, batch, psum, pcnt);
    k_final<<<N_GRAPHS, EMB, 0, stream>>>(psum, pcnt, Wp, bp, out);
}

// Round 3
// 357.532 us; speedup vs baseline: 1.3835x; 1.1197x over previous
//
#include <hip/hip_runtime.h>
#include <hip/hip_fp16.h>

#define N_NODES 50000
#define N_EDGES 600000
#define N_GRAPHS 64
#define IN_D 5
#define HID 128
#define EMB 64

#define CHUNK 512
#define NCHUNK ((N_NODES + CHUNK - 1) / CHUNK)   // 98

// ---------- CSR build ----------

__global__ void k_count(const int* __restrict__ dst, int* __restrict__ cnt) {
    int e = blockIdx.x * blockDim.x + threadIdx.x;
    if (e < N_EDGES) atomicAdd(&cnt[dst[e]], 1);
}

// per-chunk sums for scan + dinv computation (merged)
__global__ void k_chunksum(const int* __restrict__ cnt, int* __restrict__ csum,
                           float* __restrict__ dinv) {
    __shared__ int sh[256];
    int b = blockIdx.x, t = threadIdx.x;
    int i0 = b * CHUNK + t, i1 = i0 + 256;
    int v = 0;
    if (i0 < N_NODES) { int c = cnt[i0]; v += c; dinv[i0] = rsqrtf((float)c + 1.0f); }
    if (i1 < N_NODES) { int c = cnt[i1]; v += c; dinv[i1] = rsqrtf((float)c + 1.0f); }
    sh[t] = v; __syncthreads();
    for (int off = 128; off > 0; off >>= 1) {
        if (t < off) sh[t] += sh[t + off];
        __syncthreads();
    }
    if (t == 0) csum[b] = sh[0];
}

// single-wave shuffle scan over the 98 chunk sums
__global__ void k_scanchunks(int* __restrict__ csum, int* __restrict__ row_start) {
    int lane = threadIdx.x;
    int v0 = (lane < NCHUNK) ? csum[lane] : 0;
    int v1 = (lane + 64 < NCHUNK) ? csum[lane + 64] : 0;
    int s0 = v0;
    #pragma unroll
    for (int off = 1; off < 64; off <<= 1) {
        int u = __shfl_up(s0, off);
        if (lane >= off) s0 += u;
    }
    int tot0 = __shfl(s0, 63);
    int s1 = v1;
    #pragma unroll
    for (int off = 1; off < 64; off <<= 1) {
        int u = __shfl_up(s1, off);
        if (lane >= off) s1 += u;
    }
    if (lane < NCHUNK) csum[lane] = s0 - v0;                    // exclusive
    if (lane + 64 < NCHUNK) csum[lane + 64] = tot0 + s1 - v1;
    if (lane == 0) row_start[N_NODES] = N_EDGES;
}

// per-chunk exclusive scan: wave shuffle scans + 2 barriers
__global__ void k_scan(const int* __restrict__ cnt, const int* __restrict__ csum,
                       int* __restrict__ row_start) {
    __shared__ int ws[8];
    int b = blockIdx.x, t = threadIdx.x;
    int lane = t & 63, w = t >> 6;
    int i = b * CHUNK + t;
    int v = (i < N_NODES) ? cnt[i] : 0;
    int s = v;
    #pragma unroll
    for (int off = 1; off < 64; off <<= 1) {
        int u = __shfl_up(s, off);
        if (lane >= off) s += u;
    }
    if (lane == 63) ws[w] = s;
    __syncthreads();
    if (w == 0) {
        int x = (lane < 8) ? ws[lane] : 0;
        int sx = x;
        #pragma unroll
        for (int off = 1; off < 8; off <<= 1) {
            int u = __shfl_up(sx, off);
            if (lane >= off) sx += u;
        }
        if (lane < 8) ws[lane] = sx - x;   // exclusive wave offsets
    }
    __syncthreads();
    if (i < N_NODES) row_start[i] = s - v + ws[w] + csum[b];   // exclusive
}

__global__ void k_scatter(const int* __restrict__ src, const int* __restrict__ dst,
                          const float* __restrict__ dinv,
                          const int* __restrict__ row_start, int* __restrict__ fill,
                          int2* __restrict__ e_pack) {
    int e = blockIdx.x * blockDim.x + threadIdx.x;
    if (e >= N_EDGES) return;
    int d = dst[e];
    int pos = row_start[d] + atomicAdd(&fill[d], 1);
    int s = src[e];
    e_pack[pos] = make_int2(s, __float_as_int(dinv[s]));
}

// ---------- aggregation ----------

// aggregate raw x (N,5): 8 threads per node (k = lane 0..4 active)
__global__ void k_agg5(const float* __restrict__ x, const float* __restrict__ dinv,
                       const int* __restrict__ row_start,
                       const int2* __restrict__ e_pack, float* __restrict__ out) {
    int gid = blockIdx.x * blockDim.x + threadIdx.x;
    int i = gid >> 3, k = gid & 7;
    if (i >= N_NODES || k >= IN_D) return;
    float acc = 0.f;
    int beg = row_start[i], end = row_start[i + 1];
    for (int e = beg; e < end; ++e) {
        int2 p = e_pack[e];
        acc = fmaf(__int_as_float(p.y), x[p.x * IN_D + k], acc);
    }
    float di = dinv[i];
    out[i * IN_D + k] = di * (acc + di * x[i * IN_D + k]);
}

// aggregate H16 (N,128 fp16): one wave per node, one half2 per lane, unroll x4.
// 256 B per gathered row (half the fp32 traffic); fp32 accumulation.
__global__ __launch_bounds__(256) void k_agg128h(
        const __half2* __restrict__ H2, const float* __restrict__ dinv,
        const int* __restrict__ row_start, const int2* __restrict__ e_pack,
        float* __restrict__ out) {
    int wid = (blockIdx.x * blockDim.x + threadIdx.x) >> 6;
    int lane = threadIdx.x & 63;
    if (wid >= N_NODES) return;
    float2 acc = make_float2(0.f, 0.f);
    int beg = row_start[wid], end = row_start[wid + 1];
    int e = beg;
    for (; e + 3 < end; e += 4) {
        int2 p0 = e_pack[e];
        int2 p1 = e_pack[e + 1];
        int2 p2 = e_pack[e + 2];
        int2 p3 = e_pack[e + 3];
        __half2 h0 = H2[(size_t)p0.x * 64 + lane];
        __half2 h1 = H2[(size_t)p1.x * 64 + lane];
        __half2 h2 = H2[(size_t)p2.x * 64 + lane];
        __half2 h3 = H2[(size_t)p3.x * 64 + lane];
        float2 f0 = __half22float2(h0);
        float2 f1 = __half22float2(h1);
        float2 f2 = __half22float2(h2);
        float2 f3 = __half22float2(h3);
        float w0 = __int_as_float(p0.y), w1 = __int_as_float(p1.y);
        float w2 = __int_as_float(p2.y), w3 = __int_as_float(p3.y);
        acc.x = fmaf(w0, f0.x, acc.x); acc.y = fmaf(w0, f0.y, acc.y);
        acc.x = fmaf(w1, f1.x, acc.x); acc.y = fmaf(w1, f1.y, acc.y);
        acc.x = fmaf(w2, f2.x, acc.x); acc.y = fmaf(w2, f2.y, acc.y);
        acc.x = fmaf(w3, f3.x, acc.x); acc.y = fmaf(w3, f3.y, acc.y);
    }
    for (; e < end; ++e) {
        int2 p = e_pack[e];
        float w = __int_as_float(p.y);
        float2 f = __half22float2(H2[(size_t)p.x * 64 + lane]);
        acc.x = fmaf(w, f.x, acc.x);
        acc.y = fmaf(w, f.y, acc.y);
    }
    float di = dinv[wid];
    float2 hs = __half22float2(H2[(size_t)wid * 64 + lane]);
    acc.x = fmaf(di, hs.x, acc.x);
    acc.y = fmaf(di, hs.y, acc.y);
    ((float2*)out)[(size_t)wid * 64 + lane] = make_float2(di * acc.x, di * acc.y);
}

// ---------- GEMMs with fused bias + BN(eval) + ReLU ----------

// layer1: (N,5)@(5,128), 2 features per thread, fp16 output only
__global__ void k_gemm1(const float* __restrict__ A, const float* __restrict__ W,
                        const float* __restrict__ b, const float* __restrict__ g,
                        const float* __restrict__ be, __half2* __restrict__ outH) {
    int gid = blockIdx.x * blockDim.x + threadIdx.x;
    if (gid >= N_NODES * 64) return;
    int n = gid >> 6, f2 = gid & 63;
    int f = f2 * 2;
    const float* a = A + n * IN_D;
    float a0 = b[f], a1 = b[f + 1];
    #pragma unroll
    for (int k = 0; k < IN_D; ++k) {
        float ak = a[k];
        a0 = fmaf(ak, W[k * HID + f], a0);
        a1 = fmaf(ak, W[k * HID + f + 1], a1);
    }
    const float rs = rsqrtf(1.0f + 1e-5f);
    float v0 = fmaf(a0, g[f] * rs, be[f]);
    float v1 = fmaf(a1, g[f + 1] * rs, be[f + 1]);
    v0 = v0 > 0.f ? v0 : 0.f;
    v1 = v1 > 0.f ? v1 : 0.f;
    outH[(size_t)n * 64 + f2] = __floats2half2_rn(v0, v1);
}

// (N,128)@(128,128): block = 64 nodes x 64 feats, 256 threads, 64KB LDS
// OUT16: write fp16 copy only (layers 1->2, 2->3); else fp32 (layer 3 -> pool)
template <bool OUT16>
__global__ __launch_bounds__(256) void k_gemm128(
        const float* __restrict__ A, const float* __restrict__ W,
        const float* __restrict__ b, const float* __restrict__ g,
        const float* __restrict__ be, float* __restrict__ outF,
        __half2* __restrict__ outH) {
    __shared__ float4 sW[128 * 16];  // [k][f4 within half] 32KB
    __shared__ float4 sA[64 * 32];   // [n][k4] 32KB
    int t = threadIdx.x;
    int nb = blockIdx.x * 64;
    int fb4 = blockIdx.y * 16;       // feat-half base in float4 units
    const float4* W4 = (const float4*)W;
    const float4* A4 = (const float4*)A;
    #pragma unroll
    for (int i = 0; i < 8; ++i) {
        int q = t + i * 256;                 // [0,2048)
        int k = q >> 4, fv = q & 15;
        sW[q] = W4[k * 32 + fb4 + fv];
        int nl = q >> 5, kv = q & 31;
        int n = nb + nl;
        sA[q] = (n < N_NODES) ? A4[(size_t)n * 32 + kv] : make_float4(0.f, 0.f, 0.f, 0.f);
    }
    __syncthreads();
    int fi = t & 15;       // f4 within half
    int nsub = t >> 4;     // 0..15 ; nodes nsub + 16m
    float4 acc[4];
    #pragma unroll
    for (int m = 0; m < 4; ++m) acc[m] = make_float4(0.f, 0.f, 0.f, 0.f);
    for (int k4 = 0; k4 < 32; ++k4) {
        float4 a[4];
        #pragma unroll
        for (int m = 0; m < 4; ++m) a[m] = sA[(nsub + m * 16) * 32 + k4];
        #pragma unroll
        for (int j = 0; j < 4; ++j) {
            float4 w = sW[(k4 * 4 + j) * 16 + fi];
            #pragma unroll
            for (int m = 0; m < 4; ++m) {
                float aj = (j == 0) ? a[m].x : (j == 1) ? a[m].y : (j == 2) ? a[m].z : a[m].w;
                acc[m].x = fmaf(aj, w.x, acc[m].x);
                acc[m].y = fmaf(aj, w.y, acc[m].y);
                acc[m].z = fmaf(aj, w.z, acc[m].z);
                acc[m].w = fmaf(aj, w.w, acc[m].w);
            }
        }
    }
    const float rs = rsqrtf(1.0f + 1e-5f);
    float4 b4  = ((const float4*)b)[fb4 + fi];
    float4 g4  = ((const float4*)g)[fb4 + fi];
    float4 be4 = ((const float4*)be)[fb4 + fi];
    g4.x *= rs; g4.y *= rs; g4.z *= rs; g4.w *= rs;
    #pragma unroll
    for (int m = 0; m < 4; ++m) {
        int n = nb + nsub + m * 16;
        if (n < N_NODES) {
            float4 v;
            v.x = fmaf(acc[m].x + b4.x, g4.x, be4.x);
            v.y = fmaf(acc[m].y + b4.y, g4.y, be4.y);
            v.z = fmaf(acc[m].z + b4.z, g4.z, be4.z);
            v.w = fmaf(acc[m].w + b4.w, g4.w, be4.w);
            v.x = v.x > 0.f ? v.x : 0.f;
            v.y = v.y > 0.f ? v.y : 0.f;
            v.z = v.z > 0.f ? v.z : 0.f;
            v.w = v.w > 0.f ? v.w : 0.f;
            if (OUT16) {
                size_t base = (size_t)n * 64 + (size_t)(fb4 + fi) * 2;
                outH[base]     = __floats2half2_rn(v.x, v.y);
                outH[base + 1] = __floats2half2_rn(v.z, v.w);
            } else {
                ((float4*)outF)[(size_t)n * 32 + fb4 + fi] = v;
            }
        }
    }
}

// ---------- pooling + projection ----------

#define PCHUNK 64
__global__ __launch_bounds__(256) void k_pool(
        const float* __restrict__ H, const int* __restrict__ batch,
        float* __restrict__ sums, float* __restrict__ cntf) {
    int b = blockIdx.x, t = threadIdx.x;
    int f = t & 127, hv = t >> 7;   // hv = 0/1 node parity
    int n0 = b * PCHUNK + hv;
    int nend = min(b * PCHUNK + PCHUNK, N_NODES);
    float acc = 0.f, c = 0.f;
    int cur = -1;
    for (int n = n0; n < nend; n += 2) {
        int gi = batch[n];
        if (gi != cur) {
            if (cur >= 0) {
                atomicAdd(&sums[cur * HID + f], acc);
                if (f == 0) atomicAdd(&cntf[cur], c);
            }
            acc = 0.f; c = 0.f; cur = gi;
        }
        acc += H[(size_t)n * HID + f];
        c += 1.f;
    }
    if (cur >= 0) {
        atomicAdd(&sums[cur * HID + f], acc);
        if (f == 0) atomicAdd(&cntf[cur], c);
    }
}

__global__ void k_final(const float* __restrict__ sums, const float* __restrict__ cntf,
                        const float* __restrict__ Wp, const float* __restrict__ bp,
                        float* __restrict__ out) {
    int gi = blockIdx.x, e = threadIdx.x;
    float inv = 1.0f / fmaxf(cntf[gi], 1.0f);
    float acc = bp[e];
    #pragma unroll 8
    for (int f = 0; f < HID; ++f)
        acc = fmaf(sums[gi * HID + f] * inv, Wp[f * EMB + e], acc);
    out[gi * EMB + e] = acc;
}

// ---------- launcher ----------

extern "C" void kernel_launch(void* const* d_in, const int* in_sizes, int n_in,
                              void* d_out, int out_size, void* d_ws, size_t ws_size,
                              hipStream_t stream) {
    const float* x   = (const float*)d_in[0];
    const int*   src = (const int*)d_in[1];
    const int*   dst = (const int*)d_in[2];
    const int* batch = (const int*)d_in[3];
    const float* W1 = (const float*)d_in[4];
    const float* b1 = (const float*)d_in[5];
    const float* W2 = (const float*)d_in[6];
    const float* b2 = (const float*)d_in[7];
    const float* W3 = (const float*)d_in[8];
    const float* b3 = (const float*)d_in[9];
    const float* g1 = (const float*)d_in[10];
    const float* be1 = (const float*)d_in[11];
    const float* g2 = (const float*)d_in[12];
    const float* be2 = (const float*)d_in[13];
    const float* g3 = (const float*)d_in[14];
    const float* be3 = (const float*)d_in[15];
    const float* Wp = (const float*)d_in[16];
    const float* bp = (const float*)d_in[17];
    float* out = (float*)d_out;

    char* ws = (char*)d_ws;
    size_t o = 0;
    auto alloc = [&](size_t bytes) {
        void* p = ws + o;
        o += bytes;
        o = (o + 255) & ~255ull;
        return p;
    };
    int*   cnt_e     = (int*)alloc(N_NODES * 4);
    int*   row_start = (int*)alloc((N_NODES + 1) * 4);
    int*   csum      = (int*)alloc(NCHUNK * 4);
    float* dinv      = (float*)alloc(N_NODES * 4);
    int2*  e_pack    = (int2*)alloc((size_t)N_EDGES * 8);
    float* bufB      = (float*)alloc((size_t)N_NODES * HID * 4);   // agg fp32 out
    float* psum      = (float*)alloc(N_GRAPHS * HID * 4);
    float* pcnt      = (float*)alloc(N_GRAPHS * 4);
    // aliased region: agg5 (1MB) + H16 (12.8MB) live together only until layer-3
    // agg completes; bufA (25.6MB, layer-3 fp32 H for pool) reuses the whole region.
    char* region = (char*)alloc((size_t)N_NODES * HID * 4);
    float*   agg5 = (float*)region;                                   // 1 MB
    __half2* H16  = (__half2*)(region + ((size_t)N_NODES * IN_D * 4 + 255 & ~255ull));
    float*   bufA = (float*)region;

    hipMemsetAsync(cnt_e, 0, N_NODES * 4, stream);
    k_count<<<(N_EDGES + 255) / 256, 256, 0, stream>>>(dst, cnt_e);
    k_chunksum<<<NCHUNK, 256, 0, stream>>>(cnt_e, csum, dinv);
    k_scanchunks<<<1, 64, 0, stream>>>(csum, row_start);
    k_scan<<<NCHUNK, CHUNK, 0, stream>>>(cnt_e, csum, row_start);
    hipMemsetAsync(cnt_e, 0, N_NODES * 4, stream);  // reuse as fill counters
    k_scatter<<<(N_EDGES + 255) / 256, 256, 0, stream>>>(src, dst, dinv, row_start,
                                                         cnt_e, e_pack);

    // layer 1: aggregate(x) -> gemm1 (+bn+relu) -> H16
    k_agg5<<<(N_NODES * 8 + 255) / 256, 256, 0, stream>>>(x, dinv, row_start, e_pack, agg5);
    k_gemm1<<<(N_NODES * 64 + 255) / 256, 256, 0, stream>>>(agg5, W1, b1, g1, be1, H16);

    // layer 2: gather fp16 -> fp32 agg -> gemm -> H16
    k_agg128h<<<(N_NODES * 64 + 255) / 256, 256, 0, stream>>>(H16, dinv, row_start,
                                                              e_pack, bufB);
    {
        dim3 grid((N_NODES + 63) / 64, 2);
        k_gemm128<true><<<grid, 256, 0, stream>>>(bufB, W2, b2, g2, be2, nullptr, H16);
    }
    // layer 3: gather fp16 -> fp32 agg -> gemm -> bufA (fp32, aliases H16 region)
    k_agg128h<<<(N_NODES * 64 + 255) / 256, 256, 0, stream>>>(H16, dinv, row_start,
                                                              e_pack, bufB);
    {
        dim3 grid((N_NODES + 63) / 64, 2);
        k_gemm128<false><<<grid, 256, 0, stream>>>(bufB, W3, b3, g3, be3, bufA, nullptr);
    }

    // pool + project
    hipMemsetAsync(psum, 0, (N_GRAPHS * HID + N_GRAPHS) * 4, stream);
    k_pool<<<(N_NODES + PCHUNK - 1) / PCHUNK, 256, 0, stream>>>(bufA, batch, psum, pcnt);
    k_final<<<N_GRAPHS, EMB, 0, stream>>>(psum, pcnt, Wp, bp, out);
}

// Round 4
// 330.945 us; speedup vs baseline: 1.4946x; 1.0803x over previous
//
#include <hip/hip_runtime.h>
#include <hip/hip_fp16.h>

#define N_NODES 50000
#define N_EDGES 600000
#define N_GRAPHS 64
#define IN_D 5
#define HID 128
#define EMB 64

#define CHUNK 512
#define NCHUNK ((N_NODES + CHUNK - 1) / CHUNK)   // 98

typedef _Float16 half8 __attribute__((ext_vector_type(8)));
typedef float float4v __attribute__((ext_vector_type(4)));

// ---------- CSR build ----------

__global__ void k_count(const int* __restrict__ dst, int* __restrict__ cnt) {
    int e = blockIdx.x * blockDim.x + threadIdx.x;
    if (e < N_EDGES) atomicAdd(&cnt[dst[e]], 1);
}

__global__ void k_chunksum(const int* __restrict__ cnt, int* __restrict__ csum,
                           float* __restrict__ dinv) {
    __shared__ int sh[256];
    int b = blockIdx.x, t = threadIdx.x;
    int i0 = b * CHUNK + t, i1 = i0 + 256;
    int v = 0;
    if (i0 < N_NODES) { int c = cnt[i0]; v += c; dinv[i0] = rsqrtf((float)c + 1.0f); }
    if (i1 < N_NODES) { int c = cnt[i1]; v += c; dinv[i1] = rsqrtf((float)c + 1.0f); }
    sh[t] = v; __syncthreads();
    for (int off = 128; off > 0; off >>= 1) {
        if (t < off) sh[t] += sh[t + off];
        __syncthreads();
    }
    if (t == 0) csum[b] = sh[0];
}

__global__ void k_scanchunks(int* __restrict__ csum, int* __restrict__ row_start) {
    int lane = threadIdx.x;
    int v0 = (lane < NCHUNK) ? csum[lane] : 0;
    int v1 = (lane + 64 < NCHUNK) ? csum[lane + 64] : 0;
    int s0 = v0;
    #pragma unroll
    for (int off = 1; off < 64; off <<= 1) {
        int u = __shfl_up(s0, off);
        if (lane >= off) s0 += u;
    }
    int tot0 = __shfl(s0, 63);
    int s1 = v1;
    #pragma unroll
    for (int off = 1; off < 64; off <<= 1) {
        int u = __shfl_up(s1, off);
        if (lane >= off) s1 += u;
    }
    if (lane < NCHUNK) csum[lane] = s0 - v0;                    // exclusive
    if (lane + 64 < NCHUNK) csum[lane + 64] = tot0 + s1 - v1;
    if (lane == 0) row_start[N_NODES] = N_EDGES;
}

__global__ void k_scan(const int* __restrict__ cnt, const int* __restrict__ csum,
                       int* __restrict__ row_start) {
    __shared__ int ws[8];
    int b = blockIdx.x, t = threadIdx.x;
    int lane = t & 63, w = t >> 6;
    int i = b * CHUNK + t;
    int v = (i < N_NODES) ? cnt[i] : 0;
    int s = v;
    #pragma unroll
    for (int off = 1; off < 64; off <<= 1) {
        int u = __shfl_up(s, off);
        if (lane >= off) s += u;
    }
    if (lane == 63) ws[w] = s;
    __syncthreads();
    if (w == 0) {
        int x = (lane < 8) ? ws[lane] : 0;
        int sx = x;
        #pragma unroll
        for (int off = 1; off < 8; off <<= 1) {
            int u = __shfl_up(sx, off);
            if (lane >= off) sx += u;
        }
        if (lane < 8) ws[lane] = sx - x;
    }
    __syncthreads();
    if (i < N_NODES) row_start[i] = s - v + ws[w] + csum[b];
}

__global__ void k_scatter(const int* __restrict__ src, const int* __restrict__ dst,
                          const float* __restrict__ dinv,
                          const int* __restrict__ row_start, int* __restrict__ fill,
                          int2* __restrict__ e_pack) {
    int e = blockIdx.x * blockDim.x + threadIdx.x;
    if (e >= N_EDGES) return;
    int d = dst[e];
    int pos = row_start[d] + atomicAdd(&fill[d], 1);
    int s = src[e];
    e_pack[pos] = make_int2(s, __float_as_int(dinv[s]));
}

// ---------- W2/W3 -> fp16 transposed (f-major) ----------

__global__ void k_w2h(const float* __restrict__ W2, const float* __restrict__ W3,
                      _Float16* __restrict__ Wt2, _Float16* __restrict__ Wt3) {
    int id = blockIdx.x * blockDim.x + threadIdx.x;   // 0..32767
    const float* W = (id < 16384) ? W2 : W3;
    _Float16* O = (id < 16384) ? Wt2 : Wt3;
    int rem = id & 16383;
    int k = rem & 127, f = rem >> 7;
    O[rem] = (_Float16)W[k * 128 + f];   // Wt[f][k]
}

// ---------- fused layer 1: agg(x) + gemm1 + bn + relu -> H16 ----------
// 8 threads per node: thread k<5 accumulates feature k over edges; then the
// group shares the 5 sums via shuffle and each thread emits 16 output feats.

__global__ __launch_bounds__(256) void k_agg5g1(
        const float* __restrict__ x, const float* __restrict__ dinv,
        const int* __restrict__ row_start, const int2* __restrict__ e_pack,
        const float* __restrict__ W1, const float* __restrict__ b1,
        const float* __restrict__ g1, const float* __restrict__ be1,
        __half2* __restrict__ H16) {
    int gid = blockIdx.x * blockDim.x + threadIdx.x;
    int i = gid >> 3, k = gid & 7;
    if (i >= N_NODES) return;
    float acc = 0.f;
    if (k < IN_D) {
        int beg = row_start[i], end = row_start[i + 1];
        for (int e = beg; e < end; ++e) {
            int2 p = e_pack[e];
            acc = fmaf(__int_as_float(p.y), x[p.x * IN_D + k], acc);
        }
        float di = dinv[i];
        acc = di * (acc + di * x[i * IN_D + k]);
    }
    int lane = threadIdx.x & 63;
    int base = lane & ~7;
    float a0 = __shfl(acc, base + 0);
    float a1 = __shfl(acc, base + 1);
    float a2 = __shfl(acc, base + 2);
    float a3 = __shfl(acc, base + 3);
    float a4 = __shfl(acc, base + 4);
    const float rs = rsqrtf(1.0f + 1e-5f);
    int f0 = k * 16;
    #pragma unroll
    for (int u = 0; u < 8; ++u) {
        int fa = f0 + u * 2, fb = fa + 1;
        float va = b1[fa], vb = b1[fb];
        va = fmaf(a0, W1[0 * HID + fa], va); vb = fmaf(a0, W1[0 * HID + fb], vb);
        va = fmaf(a1, W1[1 * HID + fa], va); vb = fmaf(a1, W1[1 * HID + fb], vb);
        va = fmaf(a2, W1[2 * HID + fa], va); vb = fmaf(a2, W1[2 * HID + fb], vb);
        va = fmaf(a3, W1[3 * HID + fa], va); vb = fmaf(a3, W1[3 * HID + fb], vb);
        va = fmaf(a4, W1[4 * HID + fa], va); vb = fmaf(a4, W1[4 * HID + fb], vb);
        va = fmaf(va, g1[fa] * rs, be1[fa]);
        vb = fmaf(vb, g1[fb] * rs, be1[fb]);
        va = va > 0.f ? va : 0.f;
        vb = vb > 0.f ? vb : 0.f;
        H16[(size_t)i * 64 + k * 8 + u] = __floats2half2_rn(va, vb);
    }
}

// ---------- aggregation over fp16 table -> fp16 A ----------

__global__ __launch_bounds__(256) void k_agg128h(
        const __half2* __restrict__ H2, const float* __restrict__ dinv,
        const int* __restrict__ row_start, const int2* __restrict__ e_pack,
        __half2* __restrict__ A16) {
    int wid = (blockIdx.x * blockDim.x + threadIdx.x) >> 6;
    int lane = threadIdx.x & 63;
    if (wid >= N_NODES) return;
    float2 acc = make_float2(0.f, 0.f);
    int beg = row_start[wid], end = row_start[wid + 1];
    int e = beg;
    for (; e + 3 < end; e += 4) {
        int2 p0 = e_pack[e];
        int2 p1 = e_pack[e + 1];
        int2 p2 = e_pack[e + 2];
        int2 p3 = e_pack[e + 3];
        float2 f0 = __half22float2(H2[(size_t)p0.x * 64 + lane]);
        float2 f1 = __half22float2(H2[(size_t)p1.x * 64 + lane]);
        float2 f2 = __half22float2(H2[(size_t)p2.x * 64 + lane]);
        float2 f3 = __half22float2(H2[(size_t)p3.x * 64 + lane]);
        float w0 = __int_as_float(p0.y), w1 = __int_as_float(p1.y);
        float w2 = __int_as_float(p2.y), w3 = __int_as_float(p3.y);
        acc.x = fmaf(w0, f0.x, acc.x); acc.y = fmaf(w0, f0.y, acc.y);
        acc.x = fmaf(w1, f1.x, acc.x); acc.y = fmaf(w1, f1.y, acc.y);
        acc.x = fmaf(w2, f2.x, acc.x); acc.y = fmaf(w2, f2.y, acc.y);
        acc.x = fmaf(w3, f3.x, acc.x); acc.y = fmaf(w3, f3.y, acc.y);
    }
    for (; e < end; ++e) {
        int2 p = e_pack[e];
        float w = __int_as_float(p.y);
        float2 f = __half22float2(H2[(size_t)p.x * 64 + lane]);
        acc.x = fmaf(w, f.x, acc.x);
        acc.y = fmaf(w, f.y, acc.y);
    }
    float di = dinv[wid];
    float2 hs = __half22float2(H2[(size_t)wid * 64 + lane]);
    acc.x = fmaf(di, hs.x, acc.x);
    acc.y = fmaf(di, hs.y, acc.y);
    A16[(size_t)wid * 64 + lane] = __floats2half2_rn(di * acc.x, di * acc.y);
}

// ---------- MFMA GEMM: (64 nodes x 128k) @ (128k x 128f) per block ----------
// wave w handles node rows [blk*64 + w*16, +16). A fragments held in regs,
// B fragments read straight from the 32 KB fp16 Wt (L2-resident).
// Layouts (gfx950 verified): A[m=lane&15][k=quad*8+j]; B[k=quad*8+j][n=lane&15]
// via f-major Wt; C/D col=lane&15, row=quad*4+reg.

template <bool OUT16>
__global__ __launch_bounds__(256) void k_gemmM(
        const _Float16* __restrict__ A16, const _Float16* __restrict__ Wt16,
        const float* __restrict__ b, const float* __restrict__ g,
        const float* __restrict__ be,
        float* __restrict__ outF, _Float16* __restrict__ outH) {
    int t = threadIdx.x;
    int w = t >> 6, lane = t & 63;
    int quad = lane >> 4, r16 = lane & 15;
    int nb = blockIdx.x * 64 + w * 16;
    const half8* Arow = (const half8*)(A16 + (size_t)(nb + r16) * 128);
    half8 a[4];
    #pragma unroll
    for (int kb = 0; kb < 4; ++kb) a[kb] = Arow[kb * 4 + quad];
    const float rs = rsqrtf(1.0f + 1e-5f);
    #pragma unroll
    for (int ft = 0; ft < 8; ++ft) {
        int f = ft * 16 + r16;
        const half8* Brow = (const half8*)(Wt16 + (size_t)f * 128);
        float4v acc = {0.f, 0.f, 0.f, 0.f};
        #pragma unroll
        for (int kb = 0; kb < 4; ++kb) {
            half8 bf = Brow[kb * 4 + quad];
            acc = __builtin_amdgcn_mfma_f32_16x16x32_f16(a[kb], bf, acc, 0, 0, 0);
        }
        float bb = b[f], gg = g[f] * rs, bee = be[f];
        #pragma unroll
        for (int rr = 0; rr < 4; ++rr) {
            int n = nb + quad * 4 + rr;
            if (n < N_NODES) {
                float v = fmaf(acc[rr] + bb, gg, bee);
                v = v > 0.f ? v : 0.f;
                if (OUT16) outH[(size_t)n * 128 + f] = (_Float16)v;
                else       outF[(size_t)n * 128 + f] = v;
            }
        }
    }
}

// ---------- pooling + projection ----------

#define PCHUNK 64
__global__ __launch_bounds__(256) void k_pool(
        const float* __restrict__ H, const int* __restrict__ batch,
        float* __restrict__ sums, float* __restrict__ cntf) {
    int b = blockIdx.x, t = threadIdx.x;
    int f = t & 127, hv = t >> 7;
    int n0 = b * PCHUNK + hv;
    int nend = min(b * PCHUNK + PCHUNK, N_NODES);
    float acc = 0.f, c = 0.f;
    int cur = -1;
    for (int n = n0; n < nend; n += 2) {
        int gi = batch[n];
        if (gi != cur) {
            if (cur >= 0) {
                atomicAdd(&sums[cur * HID + f], acc);
                if (f == 0) atomicAdd(&cntf[cur], c);
            }
            acc = 0.f; c = 0.f; cur = gi;
        }
        acc += H[(size_t)n * HID + f];
        c += 1.f;
    }
    if (cur >= 0) {
        atomicAdd(&sums[cur * HID + f], acc);
        if (f == 0) atomicAdd(&cntf[cur], c);
    }
}

__global__ void k_final(const float* __restrict__ sums, const float* __restrict__ cntf,
                        const float* __restrict__ Wp, const float* __restrict__ bp,
                        float* __restrict__ out) {
    int gi = blockIdx.x, e = threadIdx.x;
    float inv = 1.0f / fmaxf(cntf[gi], 1.0f);
    float acc = bp[e];
    #pragma unroll 8
    for (int f = 0; f < HID; ++f)
        acc = fmaf(sums[gi * HID + f] * inv, Wp[f * EMB + e], acc);
    out[gi * EMB + e] = acc;
}

// ---------- launcher ----------

extern "C" void kernel_launch(void* const* d_in, const int* in_sizes, int n_in,
                              void* d_out, int out_size, void* d_ws, size_t ws_size,
                              hipStream_t stream) {
    const float* x   = (const float*)d_in[0];
    const int*   src = (const int*)d_in[1];
    const int*   dst = (const int*)d_in[2];
    const int* batch = (const int*)d_in[3];
    const float* W1 = (const float*)d_in[4];
    const float* b1 = (const float*)d_in[5];
    const float* W2 = (const float*)d_in[6];
    const float* b2 = (const float*)d_in[7];
    const float* W3 = (const float*)d_in[8];
    const float* b3 = (const float*)d_in[9];
    const float* g1 = (const float*)d_in[10];
    const float* be1 = (const float*)d_in[11];
    const float* g2 = (const float*)d_in[12];
    const float* be2 = (const float*)d_in[13];
    const float* g3 = (const float*)d_in[14];
    const float* be3 = (const float*)d_in[15];
    const float* Wp = (const float*)d_in[16];
    const float* bp = (const float*)d_in[17];
    float* out = (float*)d_out;

    char* ws = (char*)d_ws;
    size_t o = 0;
    auto alloc = [&](size_t bytes) {
        void* p = ws + o;
        o += bytes;
        o = (o + 255) & ~255ull;
        return p;
    };
    int*      cnt_e     = (int*)alloc(N_NODES * 4);
    int*      row_start = (int*)alloc((N_NODES + 1) * 4);
    int*      csum      = (int*)alloc(NCHUNK * 4);
    float*    dinv      = (float*)alloc(N_NODES * 4);
    int2*     e_pack    = (int2*)alloc((size_t)N_EDGES * 8);
    _Float16* Wt2       = (_Float16*)alloc(16384 * 2);
    _Float16* Wt3       = (_Float16*)alloc(16384 * 2);
    __half2*  H16       = (__half2*)alloc((size_t)N_NODES * HID * 2);        // gather table
    __half2*  A16       = (__half2*)alloc((size_t)(N_NODES + 64) * HID * 2); // agg out (+pad rows)
    float*    bufA      = (float*)alloc((size_t)N_NODES * HID * 4);          // layer-3 fp32
    float*    psum      = (float*)alloc(N_GRAPHS * HID * 4);
    float*    pcnt      = (float*)alloc(N_GRAPHS * 4);

    hipMemsetAsync(cnt_e, 0, N_NODES * 4, stream);
    k_w2h<<<128, 256, 0, stream>>>(W2, W3, Wt2, Wt3);
    k_count<<<(N_EDGES + 255) / 256, 256, 0, stream>>>(dst, cnt_e);
    k_chunksum<<<NCHUNK, 256, 0, stream>>>(cnt_e, csum, dinv);
    k_scanchunks<<<1, 64, 0, stream>>>(csum, row_start);
    k_scan<<<NCHUNK, CHUNK, 0, stream>>>(cnt_e, csum, row_start);
    hipMemsetAsync(cnt_e, 0, N_NODES * 4, stream);  // reuse as fill counters
    k_scatter<<<(N_EDGES + 255) / 256, 256, 0, stream>>>(src, dst, dinv, row_start,
                                                         cnt_e, e_pack);

    // layer 1 (fused agg + gemm + bn + relu) -> H16
    k_agg5g1<<<(N_NODES * 8 + 255) / 256, 256, 0, stream>>>(x, dinv, row_start, e_pack,
                                                            W1, b1, g1, be1, H16);
    // layer 2
    k_agg128h<<<(N_NODES * 64 + 255) / 256, 256, 0, stream>>>(H16, dinv, row_start,
                                                              e_pack, A16);
    k_gemmM<true><<<(N_NODES + 63) / 64, 256, 0, stream>>>((const _Float16*)A16, Wt2,
                                                           b2, g2, be2, nullptr,
                                                           (_Float16*)H16);
    // layer 3
    k_agg128h<<<(N_NODES * 64 + 255) / 256, 256, 0, stream>>>(H16, dinv, row_start,
                                                              e_pack, A16);
    k_gemmM<false><<<(N_NODES + 63) / 64, 256, 0, stream>>>((const _Float16*)A16, Wt3,
                                                            b3, g3, be3, bufA, nullptr);

    // pool + project
    hipMemsetAsync(psum, 0, (N_GRAPHS * HID + N_GRAPHS) * 4, stream);
    k_pool<<<(N_NODES + PCHUNK - 1) / PCHUNK, 256, 0, stream>>>(bufA, batch, psum, pcnt);
    k_final<<<N_GRAPHS, EMB, 0, stream>>>(psum, pcnt, Wp, bp, out);
}